// Round 3
// baseline (237.093 us; speedup 1.0000x reference)
//
#include <hip/hip_runtime.h>

#define BB    8
#define LQN   2048
#define LKVN  2048
#define DQ    128
#define DVN   128
#define QT    16      // Q rows per block
#define KT    64      // phase-2 KV tile
#define KT1   128     // phase-1 KV tile
#define NT    (LKVN / KT)    // 32
#define NT1   (LKVN / KT1)   // 16
#define KSTR  136     // k_lds row stride (bf16): b128 reads conflict-free
#define VSTR  72
#define PSTR  72

typedef short short8 __attribute__((ext_vector_type(8)));
typedef float f32x4  __attribute__((ext_vector_type(4)));

// LDS-only barrier: does NOT drain global stores/loads (vmcnt untouched).
#define BAR() asm volatile("s_waitcnt lgkmcnt(0)\n\ts_barrier" ::: "memory")

__device__ __forceinline__ short f2bf(float f) {
  unsigned u = __builtin_bit_cast(unsigned, f);
  u += 0x7fffu + ((u >> 16) & 1u);   // round-to-nearest-even
  return (short)(u >> 16);
}

// Q,K fp32 -> bf16 row-major
__global__ __launch_bounds__(256) void conv_kernel(const float* __restrict__ Q,
                                                   const float* __restrict__ K,
                                                   short* __restrict__ Qb,
                                                   short* __restrict__ Kb) {
  int i = blockIdx.x * 256 + threadIdx.x;
  const float* s; short* d;
  if (i < 262144) { s = Q; d = Qb; }
  else            { s = K; d = Kb; i -= 262144; }
  size_t off = (size_t)i * 8;
  float4 a = *(const float4*)(s + off);
  float4 b = *(const float4*)(s + off + 4);
  short8 o;
  o[0] = f2bf(a.x); o[1] = f2bf(a.y); o[2] = f2bf(a.z); o[3] = f2bf(a.w);
  o[4] = f2bf(b.x); o[5] = f2bf(b.y); o[6] = f2bf(b.z); o[7] = f2bf(b.w);
  *(short8*)(d + off) = o;
}

// V (B, LKV, DV) fp32 -> Vt (B, DV, LKV) bf16
__global__ __launch_bounds__(256) void vtrans_kernel(const float* __restrict__ V,
                                                     short* __restrict__ Vt) {
  __shared__ float tile[128][33];
  const int kv0 = blockIdx.x * 128;
  const int dv0 = blockIdx.y * 32;
  const int b   = blockIdx.z;
  const int tid = threadIdx.x;
  const float* src = V + ((size_t)b * LKVN + kv0) * DVN + dv0;
#pragma unroll
  for (int it = 0; it < 4; ++it) {
    int idx = it * 256 + tid;
    int r = idx >> 3, c4 = idx & 7;
    float4 v = *(const float4*)(src + (size_t)r * DVN + c4 * 4);
    tile[r][c4 * 4 + 0] = v.x;
    tile[r][c4 * 4 + 1] = v.y;
    tile[r][c4 * 4 + 2] = v.z;
    tile[r][c4 * 4 + 3] = v.w;
  }
  __syncthreads();
  short* dst = Vt + ((size_t)b * DVN + dv0) * LKVN + kv0;
#pragma unroll
  for (int it = 0; it < 2; ++it) {
    int idx = it * 256 + tid;
    int row = idx >> 4, ch = idx & 15;
    short8 o;
#pragma unroll
    for (int j = 0; j < 8; ++j) o[j] = f2bf(tile[ch * 8 + j][row]);
    *(short8*)(dst + (size_t)row * LKVN + ch * 8) = o;
  }
}

// LDS layout (bytes), union of phases:
//   phase 1: k1[128][KSTR]                      0 .. 34816
//   phase 2: k2[64][KSTR]                       0 .. 17408
//            v [128][VSTR]                  17408 .. 35840
//            p [2][QT][PSTR]                35840 .. 40448
//   both:    red[4][QT] 40448..40704, statr[QT] 40704..40768
#define SMEM_BYTES 40768

__global__ __launch_bounds__(256, 4) void attn_kernel(const short* __restrict__ Qb,
                                                      const short* __restrict__ Kb,
                                                      const short* __restrict__ Vt,
                                                      float* __restrict__ W,
                                                      float* __restrict__ O) {
  __shared__ __align__(16) char smem[SMEM_BYTES];
  short (*k1)[KSTR] = (short(*)[KSTR])smem;
  short (*k2)[KSTR] = (short(*)[KSTR])smem;
  short (*vl)[VSTR] = (short(*)[VSTR])(smem + 17408);
  short (*pl)[QT][PSTR] = (short(*)[QT][PSTR])(smem + 35840);
  float (*redl)[QT] = (float(*)[QT])(smem + 40448);
  float* statr = (float*)(smem + 40704);

  const int tid  = threadIdx.x;
  const int w    = tid >> 6;
  const int lane = tid & 63;
  const int n    = lane & 15;
  const int qd   = lane >> 4;
  const int b    = blockIdx.x & 7;          // batch -> XCD-pinned L2 locality
  const int q0   = (blockIdx.x >> 3) * QT;

  const short* Kbase = Kb + (size_t)b * LKVN * DQ;
  const short* Vbase = Vt + (size_t)b * DVN * LKVN;

  const int kr = tid >> 4, kc = tid & 15;   // K staging: rows kr+16*it, chunk kc
  const int vr = tid >> 3, vc = tid & 7;    // V staging: rows vr+32*it, chunk vc

  // Q A-frags, registers for both phases
  short8 qf[4];
  {
    const short* Qrow = Qb + ((size_t)b * LQN + q0 + n) * DQ + qd * 8;
#pragma unroll
    for (int ks = 0; ks < 4; ++ks) qf[ks] = *(const short8*)(Qrow + ks * 32);
  }

  const float scale = 0.08838834764831845f;  // 1/sqrt(128)
  float l_part[4] = {0.f, 0.f, 0.f, 0.f};

  // ---------------- phase 1: l = row sums of exp(s), KT1=128 tiles ----------------
  {
    short8 kreg[8];
#pragma unroll
    for (int it = 0; it < 8; ++it)
      kreg[it] = *(const short8*)(Kbase + (size_t)(kr + it * 16) * DQ + kc * 8);
#pragma unroll
    for (int it = 0; it < 8; ++it)
      *(short8*)&k1[kr + it * 16][kc * 8] = kreg[it];
    BAR();

    for (int t = 0; t < NT1; ++t) {
      short8 bf[2][4];
#pragma unroll
      for (int c = 0; c < 2; ++c)
#pragma unroll
        for (int ks = 0; ks < 4; ++ks)
          bf[c][ks] = *(const short8*)&k1[c * 64 + w * 16 + n][ks * 32 + qd * 8];
      BAR();                                   // k1 free for restage
      if (t + 1 < NT1) {
        const short* src = Kbase + (size_t)(t + 1) * KT1 * DQ;
#pragma unroll
        for (int it = 0; it < 8; ++it)
          kreg[it] = *(const short8*)(src + (size_t)(kr + it * 16) * DQ + kc * 8);
      }
      f32x4 a0 = {0.f, 0.f, 0.f, 0.f}, a1 = {0.f, 0.f, 0.f, 0.f};
#pragma unroll
      for (int ks = 0; ks < 4; ++ks) {
        a0 = __builtin_amdgcn_mfma_f32_16x16x32_bf16(qf[ks], bf[0][ks], a0, 0, 0, 0);
        a1 = __builtin_amdgcn_mfma_f32_16x16x32_bf16(qf[ks], bf[1][ks], a1, 0, 0, 0);
      }
#pragma unroll
      for (int r = 0; r < 4; ++r)
        l_part[r] += __expf(a0[r] * scale) + __expf(a1[r] * scale);
      if (t + 1 < NT1) {
#pragma unroll
        for (int it = 0; it < 8; ++it)
          *(short8*)&k1[kr + it * 16][kc * 8] = kreg[it];
      }
      BAR();                                   // staging visible
    }
  }

  // reduce l across the 16 n-lanes, then across waves
#pragma unroll
  for (int r = 0; r < 4; ++r)
#pragma unroll
    for (int off = 1; off < 16; off <<= 1)
      l_part[r] += __shfl_xor(l_part[r], off, 64);
  if (n == 0)
#pragma unroll
    for (int r = 0; r < 4; ++r) redl[w][qd * 4 + r] = l_part[r];
  __syncthreads();
  if (tid < QT)
    statr[tid] = 1.0f / (redl[0][tid] + redl[1][tid] + redl[2][tid] + redl[3][tid]);
  __syncthreads();
  float rinv[4];
#pragma unroll
  for (int r = 0; r < 4; ++r) rinv[r] = statr[qd * 4 + r];

  // ---------------- phase 2: W = P (normalized) + O = P V ----------------
  f32x4 oacc[2];
  oacc[0] = (f32x4){0.f, 0.f, 0.f, 0.f};
  oacc[1] = (f32x4){0.f, 0.f, 0.f, 0.f};
  float* Wb = W + ((size_t)b * LQN + q0) * LKVN;

  short8 kreg[4], vreg[4];
#pragma unroll
  for (int it = 0; it < 4; ++it)
    kreg[it] = *(const short8*)(Kbase + (size_t)(kr + it * 16) * DQ + kc * 8);
#pragma unroll
  for (int it = 0; it < 4; ++it)
    vreg[it] = *(const short8*)(Vbase + (size_t)(vr + it * 32) * LKVN + vc * 8);
#pragma unroll
  for (int it = 0; it < 4; ++it)
    *(short8*)&k2[kr + it * 16][kc * 8] = kreg[it];
#pragma unroll
  for (int it = 0; it < 4; ++it)
    *(short8*)&vl[vr + it * 32][vc * 8] = vreg[it];
  BAR();

  for (int t = 0; t < NT; ++t) {
    const int kv0 = t * KT;
    // read all frags for this tile into registers
    short8 bf[4], vf[2][2];
#pragma unroll
    for (int ks = 0; ks < 4; ++ks)
      bf[ks] = *(const short8*)&k2[w * 16 + n][ks * 32 + qd * 8];
#pragma unroll
    for (int c = 0; c < 2; ++c) {
      vf[c][0] = *(const short8*)&vl[w * 32 + c * 16 + n][qd * 8];
      vf[c][1] = *(const short8*)&vl[w * 32 + c * 16 + n][32 + qd * 8];
    }
    BAR();                                     // k2/vl free for restage
    if (t + 1 < NT) {
      const short* ksrc = Kbase + (size_t)(kv0 + KT) * DQ;
      const short* vsrc = Vbase + kv0 + KT;
#pragma unroll
      for (int it = 0; it < 4; ++it)
        kreg[it] = *(const short8*)(ksrc + (size_t)(kr + it * 16) * DQ + kc * 8);
#pragma unroll
      for (int it = 0; it < 4; ++it)
        vreg[it] = *(const short8*)(vsrc + (size_t)(vr + it * 32) * LKVN + vc * 8);
    }
    f32x4 acc = {0.f, 0.f, 0.f, 0.f};
#pragma unroll
    for (int ks = 0; ks < 4; ++ks)
      acc = __builtin_amdgcn_mfma_f32_16x16x32_bf16(qf[ks], bf[ks], acc, 0, 0, 0);
    float p[4];
#pragma unroll
    for (int r = 0; r < 4; ++r) p[r] = __expf(acc[r] * scale) * rinv[r];
#pragma unroll
    for (int r = 0; r < 4; ++r)
      Wb[(size_t)(qd * 4 + r) * LKVN + kv0 + w * 16 + n] = p[r];   // fire-and-forget
#pragma unroll
    for (int r = 0; r < 4; ++r) pl[t & 1][qd * 4 + r][w * 16 + n] = f2bf(p[r]);
    if (t + 1 < NT) {
#pragma unroll
      for (int it = 0; it < 4; ++it)
        *(short8*)&k2[kr + it * 16][kc * 8] = kreg[it];
#pragma unroll
      for (int it = 0; it < 4; ++it)
        *(short8*)&vl[vr + it * 32][vc * 8] = vreg[it];
    }
    BAR();                                     // p ready + staging visible
    short8 pa0 = *(const short8*)&pl[t & 1][n][qd * 8];
    short8 pa1 = *(const short8*)&pl[t & 1][n][32 + qd * 8];
#pragma unroll
    for (int c = 0; c < 2; ++c) {
      oacc[c] = __builtin_amdgcn_mfma_f32_16x16x32_bf16(pa0, vf[c][0], oacc[c], 0, 0, 0);
      oacc[c] = __builtin_amdgcn_mfma_f32_16x16x32_bf16(pa1, vf[c][1], oacc[c], 0, 0, 0);
    }
  }

  float* Ob = O + ((size_t)b * LQN + q0) * DVN;
#pragma unroll
  for (int c = 0; c < 2; ++c)
#pragma unroll
    for (int r = 0; r < 4; ++r)
      Ob[(size_t)(qd * 4 + r) * DVN + w * 32 + c * 16 + n] = oacc[c][r];
}

extern "C" void kernel_launch(void* const* d_in, const int* in_sizes, int n_in,
                              void* d_out, int out_size, void* d_ws, size_t ws_size,
                              hipStream_t stream) {
  const float* Q = (const float*)d_in[0];
  const float* K = (const float*)d_in[1];
  const float* V = (const float*)d_in[2];
  float* W = (float*)d_out;                        // (B, LQ, LKV)
  float* O = W + (size_t)BB * LQN * LKVN;          // (B, LQ, DV)
  short* Qb = (short*)d_ws;
  short* Kb = Qb + (size_t)BB * LQN * DQ;
  short* Vt = Kb + (size_t)BB * LKVN * DQ;

  conv_kernel<<<2048, 256, 0, stream>>>(Q, K, Qb, Kb);
  vtrans_kernel<<<dim3(LKVN / 128, DVN / 32, BB), 256, 0, stream>>>(V, Vt);
  attn_kernel<<<1024, 256, 0, stream>>>(Qb, Kb, Vt, W, O);
}